// Round 3
// baseline (576.959 us; speedup 1.0000x reference)
//
#include <hip/hip_runtime.h>

// B=256, F=16, FO=32, J=22, H=8, IN=256, OUT=512, HID=64, HS=32
// Degenerate-einsum analysis:
//   attn_s = qsum (x) ksum  (outer product of channel sums)
//   x_s    = diag(softmax(attn_s)) * (sum_u v_s')
//   x_t    = sum_f v_t  (softmax sums to 1; q_t/k_t/conv_t/mask_t unused)
// Round 2: vproj restructured — ks-outer loop (A-frags hoisted, 48 LDS reads
// per wave not 192), LDS rows padded to 528B (conflict-free), Wv pre-swizzled
// into per-wave fragment order (coalesced 1KB B-loads, L2-hot).

#define NEGV (-1000000000.0f)

typedef __attribute__((ext_vector_type(8))) short short8;
typedef __attribute__((ext_vector_type(4))) float f32x4;

__device__ inline ushort f2bf(float f) {
  union { float f; unsigned u; } a;
  a.f = f;
  unsigned u = a.u;
  return (ushort)((u + 0x7FFFu + ((u >> 16) & 1u)) >> 16);  // RNE
}

// ---------------- prep: pre-summed weight columns ----------------
__global__ void prep_kernel(const float* __restrict__ Wq_w, const float* __restrict__ Wq_b,
                            const float* __restrict__ Wk_w, const float* __restrict__ Wk_b,
                            float* __restrict__ sqw, float* __restrict__ sqb,
                            float* __restrict__ skw, float* __restrict__ skb) {
  int i = threadIdx.x;  // 0..255
  for (int m = 0; m < 8; ++m) {
    float aq = 0.f, ak = 0.f;
    #pragma unroll
    for (int c = 0; c < 32; ++c) {
      aq += Wq_w[i * 512 + m * 64 + c];
      ak += Wk_w[i * 512 + m * 64 + c];
    }
    sqw[i * 8 + m] = aq;
    skw[i * 8 + m] = ak;
  }
  if (i < 8) {
    float aq = 0.f, ak = 0.f;
    for (int c = 0; c < 32; ++c) { aq += Wq_b[i * 64 + c]; ak += Wk_b[i * 64 + c]; }
    sqb[i] = aq;
    skb[i] = ak;
  }
}

// ---------------- Wv -> bf16 swizzled to wave-fragment order ----------------
// wvtf[((nt*8 + ks)*64 + lane)*8 + e] = bf16(Wv[(ks*32 + (lane>>4)*8 + e)*512 + nt*16 + (lane&15)])
__global__ __launch_bounds__(512) void wvt_kernel(const float* __restrict__ Wv,
                                                  ushort* __restrict__ wvtf) {
  int idx = blockIdx.x * 512 + threadIdx.x;  // 0..131071
  int e = idx & 7;
  int lane = (idx >> 3) & 63;
  int ks = (idx >> 9) & 7;
  int nt = idx >> 12;
  int r0 = lane & 15, kb = lane >> 4;
  int k = ks * 32 + kb * 8 + e;
  int ch = nt * 16 + r0;
  wvtf[idx] = f2bf(Wv[k * 512 + ch]);
}

// ---------------- qsum[b][h][t][s] = sum_c q_s ----------------
__global__ __launch_bounds__(256) void qsum_kernel(const float* __restrict__ q,
                                                   const float* __restrict__ sqw,
                                                   const float* __restrict__ sqb,
                                                   float* __restrict__ qsum) {
  int blk = blockIdx.x;  // b*32 + fo2
  int fo2 = blk & 31;
  int b = blk >> 5;
  __shared__ float lq[22][257];
  __shared__ float lw[2048];
  __shared__ float lb[8];
  int tid = threadIdx.x;
  const float* qb = q + (size_t)blk * (22 * 256);
  #pragma unroll
  for (int j = 0; j < 22; ++j) lq[j][tid] = qb[j * 256 + tid];
  for (int r = tid; r < 2048; r += 256) lw[r] = sqw[r];
  if (tid < 8) lb[tid] = sqb[tid];
  __syncthreads();
  if (tid < 176) {
    int j2 = tid >> 3, m = tid & 7;
    float acc = lb[m];
    for (int i = 0; i < 256; ++i) acc += lq[j2][i] * lw[i * 8 + m];
    int lf = (fo2 & 3) * 11264 + j2 * 512 + m * 64;
    int t = lf / 1408;
    int s = (lf % 1408) >> 6;
    int h = fo2 >> 2;
    qsum[(((size_t)b * 8 + h) * 32 + t) * 22 + s] = acc;
  }
}

// ---------------- ksumraw[b][h][f][j] = sum_d k_s ----------------
__global__ __launch_bounds__(256) void ksum_kernel(const float* __restrict__ k,
                                                   const float* __restrict__ skw,
                                                   const float* __restrict__ skb,
                                                   float* __restrict__ ksumraw) {
  int blk = blockIdx.x;  // b*16 + f2
  int f2 = blk & 15;
  int b = blk >> 4;
  __shared__ float lk[22][257];
  __shared__ float lw[2048];
  __shared__ float lb[8];
  int tid = threadIdx.x;
  const float* kb = k + (size_t)blk * (22 * 256);
  #pragma unroll
  for (int j = 0; j < 22; ++j) lk[j][tid] = kb[j * 256 + tid];
  for (int r = tid; r < 2048; r += 256) lw[r] = skw[r];
  if (tid < 8) lb[tid] = skb[tid];
  __syncthreads();
  if (tid < 176) {
    int j2 = tid >> 3, m = tid & 7;
    float acc = lb[m];
    for (int i = 0; i < 256; ++i) acc += lk[j2][i] * lw[i * 8 + m];
    int lf = (f2 & 1) * 11264 + j2 * 512 + m * 64;
    int floc = lf / 1408;
    int j = (lf % 1408) >> 6;
    int h = f2 >> 1;
    ksumraw[(((size_t)b * 8 + h) * 16 + floc) * 22 + j] = acc;
  }
}

// ---------------- ksum_s = conv_s over ksumraw ----------------
__global__ void convk_kernel(const float* __restrict__ ksumraw, const float* __restrict__ csw,
                             const float* __restrict__ csb, float* __restrict__ ksum_s) {
  size_t idx = (size_t)blockIdx.x * 256 + threadIdx.x;
  if (idx >= (size_t)256 * 8 * 32 * 22) return;
  int j = (int)(idx % 22);
  size_t r = idx / 22;
  int o = (int)(r % 32);
  size_t bh = r / 32;
  float acc = 32.0f * csb[o];
  #pragma unroll
  for (int f = 0; f < 16; ++f) acc += csw[o * 16 + f] * ksumraw[(bh * 16 + f) * 22 + j];
  ksum_s[idx] = acc;
}

// ---------------- V projection via MFMA + scatter-reduce ----------------
// Block per (b,h): A = 44x256 bf16 in LDS (rows padded to 264 ushorts),
// B = wvtf (pre-swizzled, coalesced 16B/lane loads, L2-hot).
// ks-outer loop, n-tiles in 2 halves of 4 (acc in regs), scatter-reduce
// into vs_acc[16][32] (sum over j') and vt_acc[22][32] (sum over f').
__global__ __launch_bounds__(256) void vproj_mfma_kernel(const float* __restrict__ v,
                                                         const ushort* __restrict__ wvtf,
                                                         const float* __restrict__ Wv_b,
                                                         float* __restrict__ vs_inner,
                                                         float* __restrict__ vtsum) {
  int bh = blockIdx.x;
  __shared__ ushort lA[48 * 264];
  __shared__ float vs_acc[512];
  __shared__ float vt_acc[704];
  int tid = threadIdx.x;

  // stage A: 44x256 f32 -> bf16, padded rows
  const float4* vb4 = reinterpret_cast<const float4*>(v + (size_t)bh * (44 * 256));
  #pragma unroll
  for (int it = 0; it < 11; ++it) {
    int idx = tid + it * 256;  // float4 index: row = idx>>6, c4 = idx&63
    int row = idx >> 6, c4 = idx & 63;
    float4 x = vb4[idx];
    ushort4 u;
    u.x = f2bf(x.x);
    u.y = f2bf(x.y);
    u.z = f2bf(x.z);
    u.w = f2bf(x.w);
    *reinterpret_cast<ushort4*>(&lA[row * 264 + c4 * 4]) = u;
  }
  {  // zero rows 44..47 (cols 0..255)
    ushort4 z = {0, 0, 0, 0};
    int row = 44 + (tid >> 6), c4 = tid & 63;
    *reinterpret_cast<ushort4*>(&lA[row * 264 + c4 * 4]) = z;
  }
  vs_acc[tid] = 0.f;
  vs_acc[tid + 256] = 0.f;
  for (int r = tid; r < 704; r += 256) vt_acc[r] = 0.f;
  __syncthreads();

  int lane = tid & 63, wid = tid >> 6;
  int r0 = lane & 15, kb = lane >> 4;

  #pragma unroll
  for (int half = 0; half < 2; ++half) {
    // this half's 4 n-tiles: nt = wid*8 + half*4 + nt4
    f32x4 acc[4][3];
    #pragma unroll
    for (int n = 0; n < 4; ++n)
      #pragma unroll
      for (int m = 0; m < 3; ++m)
        acc[n][m] = (f32x4){0.f, 0.f, 0.f, 0.f};

    int nt0 = wid * 8 + half * 4;
    #pragma unroll
    for (int ks = 0; ks < 8; ++ks) {
      short8 a0 = *reinterpret_cast<const short8*>(&lA[(r0) * 264 + ks * 32 + kb * 8]);
      short8 a1 = *reinterpret_cast<const short8*>(&lA[(16 + r0) * 264 + ks * 32 + kb * 8]);
      short8 a2 = *reinterpret_cast<const short8*>(&lA[(32 + r0) * 264 + ks * 32 + kb * 8]);
      const ushort* bb = wvtf + ((size_t)(nt0 * 8 + ks) * 64 + lane) * 8;
      #pragma unroll
      for (int n = 0; n < 4; ++n) {
        short8 bf = *reinterpret_cast<const short8*>(bb + (size_t)n * 4096);
        acc[n][0] = __builtin_amdgcn_mfma_f32_16x16x32_bf16(a0, bf, acc[n][0], 0, 0, 0);
        acc[n][1] = __builtin_amdgcn_mfma_f32_16x16x32_bf16(a1, bf, acc[n][1], 0, 0, 0);
        acc[n][2] = __builtin_amdgcn_mfma_f32_16x16x32_bf16(a2, bf, acc[n][2], 0, 0, 0);
      }
    }

    #pragma unroll
    for (int n = 0; n < 4; ++n) {
      int nt = nt0 + n;
      int ch = nt * 16 + r0;
      float bias = Wv_b[ch];
      int c6 = nt >> 2;  // == ch>>6 since r0<16
      int d = ch & 63;
      #pragma unroll
      for (int m = 0; m < 3; ++m) {
        #pragma unroll
        for (int reg = 0; reg < 4; ++reg) {
          int gr = m * 16 + kb * 4 + reg;  // D row = (lane>>4)*4 + reg (m89-verified)
          if (gr >= 44) continue;
          int f2loc = (gr >= 22) ? 1 : 0;
          int j = gr - f2loc * 22;
          int fj = f2loc * 176 + j * 8 + c6;
          int f = fj / 22;
          int jj = fj - f * 22;
          float val = acc[n][m][reg] + bias;
          if (d < 32)
            atomicAdd(&vs_acc[f * 32 + d], val);
          else
            atomicAdd(&vt_acc[jj * 32 + (d - 32)], val);
        }
      }
    }
  }
  __syncthreads();
  float* vsg = vs_inner + (size_t)bh * 512;
  float* vtg = vtsum + (size_t)bh * 704;
  vsg[tid] = vs_acc[tid];
  vsg[tid + 256] = vs_acc[tid + 256];
  for (int r = tid; r < 704; r += 256) vtg[r] = vt_acc[r];
}

// ---------------- vssum = conv_s over vs_inner ----------------
__global__ void convv_kernel(const float* __restrict__ vs_inner, const float* __restrict__ csw,
                             const float* __restrict__ csb, float* __restrict__ vssum) {
  size_t idx = (size_t)blockIdx.x * 256 + threadIdx.x;
  if (idx >= (size_t)256 * 8 * 32 * 32) return;
  int d = (int)(idx & 31);
  size_t r = idx >> 5;
  int t = (int)(r & 31);
  size_t bh = r >> 5;
  float acc = 22.0f * csb[t];
  #pragma unroll
  for (int f = 0; f < 16; ++f) acc += csw[t * 16 + f] * vs_inner[(bh * 16 + f) * 32 + d];
  vssum[idx] = acc;
}

// ---------------- final: diag softmax + assemble output ----------------
__global__ __launch_bounds__(256) void final_kernel(const float* __restrict__ qsum,
                                                    const float* __restrict__ ksum_s,
                                                    const float* __restrict__ vssum,
                                                    const float* __restrict__ vtsum,
                                                    const int* __restrict__ mask_s,
                                                    float* __restrict__ out) {
  int blk = blockIdx.x;  // b*32 + t
  int t = blk & 31;
  int b = blk >> 5;
  __shared__ float ql[8][22], kl[8][22], vsl[8][32], dg[8][22];
  __shared__ float vtl[8][704];
  __shared__ int msk[484];
  int tid = threadIdx.x;
  size_t bbase = (size_t)b * 8;
  if (tid < 176) {
    int h = tid / 22, s = tid % 22;
    ql[h][s] = qsum[((bbase + h) * 32 + t) * 22 + s];
    kl[h][s] = ksum_s[((bbase + h) * 32 + t) * 22 + s];
  }
  {
    int h = tid >> 5, d = tid & 31;
    vsl[h][d] = vssum[((bbase + h) * 32 + t) * 32 + d];
  }
  for (int idx = tid; idx < 5632; idx += 256) {
    int h = idx / 704, r = idx % 704;
    vtl[h][r] = vtsum[(bbase + h) * 704 + r];
  }
  for (int idx = tid; idx < 484; idx += 256) msk[idx] = mask_s[idx];
  __syncthreads();
  if (tid < 176) {
    int h = tid / 22, s = tid % 22;
    float qv = ql[h][s];
    float mx = -3.0e38f;
    #pragma unroll
    for (int u = 0; u < 22; ++u) {
      float av = msk[s * 22 + u] ? qv * kl[h][u] : NEGV;
      mx = fmaxf(mx, av);
    }
    float den = 0.f;
    #pragma unroll
    for (int u = 0; u < 22; ++u) {
      float av = msk[s * 22 + u] ? qv * kl[h][u] : NEGV;
      den += expf(av - mx);
    }
    float as = msk[s * 22 + s] ? qv * kl[h][s] : NEGV;
    dg[h][s] = expf(as - mx) / den;
  }
  __syncthreads();
  float* ob = out + (size_t)blk * (22 * 512);
  for (int idx = tid; idx < 11264; idx += 256) {
    int s = idx >> 9;
    int ch = idx & 511;
    int h = ch >> 6;
    int d = ch & 63;
    float val = (d < 32) ? dg[h][s] * vsl[h][d] : vtl[h][s * 32 + (d & 31)];
    ob[idx] = val;
  }
}

extern "C" void kernel_launch(void* const* d_in, const int* in_sizes, int n_in,
                              void* d_out, int out_size, void* d_ws, size_t ws_size,
                              hipStream_t stream) {
  const float* q = (const float*)d_in[0];
  const float* k = (const float*)d_in[1];
  const float* v = (const float*)d_in[2];
  const int* mask_s = (const int*)d_in[3];
  const float* Wq_w = (const float*)d_in[5];
  const float* Wq_b = (const float*)d_in[6];
  const float* Wk_w = (const float*)d_in[7];
  const float* Wk_b = (const float*)d_in[8];
  const float* Wv_w = (const float*)d_in[9];
  const float* Wv_b = (const float*)d_in[10];
  const float* csw = (const float*)d_in[11];
  const float* csb = (const float*)d_in[12];
  float* out = (float*)d_out;

  float* ws = (float*)d_ws;
  float* sqw = ws;                         // 2048
  float* sqb = sqw + 2048;                 // 8
  float* skw = sqb + 8;                    // 2048
  float* skb = skw + 2048;                 // 8
  ushort* wvtf = (ushort*)(skb + 8);       // 131072 ushorts
  float* qsum = (float*)(wvtf + 131072);   // 1441792
  float* ksumraw = qsum + 1441792;         // 720896
  float* ksum_s = ksumraw + 720896;        // 1441792
  float* vs_inner = ksum_s + 1441792;      // 1048576
  float* vtsum = vs_inner + 1048576;       // 1441792
  float* vssum = vtsum + 1441792;          // 2097152

  hipLaunchKernelGGL(prep_kernel, dim3(1), dim3(256), 0, stream,
                     Wq_w, Wq_b, Wk_w, Wk_b, sqw, sqb, skw, skb);
  hipLaunchKernelGGL(wvt_kernel, dim3(256), dim3(512), 0, stream, Wv_w, wvtf);
  hipLaunchKernelGGL(qsum_kernel, dim3(256 * 32), dim3(256), 0, stream, q, sqw, sqb, qsum);
  hipLaunchKernelGGL(ksum_kernel, dim3(256 * 16), dim3(256), 0, stream, k, skw, skb, ksumraw);
  hipLaunchKernelGGL(convk_kernel, dim3(5632), dim3(256), 0, stream, ksumraw, csw, csb, ksum_s);
  hipLaunchKernelGGL(vproj_mfma_kernel, dim3(2048), dim3(256), 0, stream,
                     v, wvtf, Wv_b, vs_inner, vtsum);
  hipLaunchKernelGGL(convv_kernel, dim3(8192), dim3(256), 0, stream, vs_inner, csw, csb, vssum);
  hipLaunchKernelGGL(final_kernel, dim3(8192), dim3(256), 0, stream,
                     qsum, ksum_s, vssum, vtsum, mask_s, out);
}

// Round 4
// 537.186 us; speedup vs baseline: 1.0740x; 1.0740x over previous
//
#include <hip/hip_runtime.h>

// B=256, F=16, FO=32, J=22, H=8, IN=256, OUT=512, HID=64, HS=32
// Degenerate-einsum analysis:
//   attn_s = qsum (x) ksum  (outer product of channel sums)
//   x_s    = diag(softmax(attn_s)) * (sum_u v_s')
//   x_t    = sum_f v_t  (softmax sums to 1; q_t/k_t/conv_t/mask_t unused)
// Round 4: vproj2 — block covers 8 bh x 256-ch slice; B-frags loop-invariant
// (LICM into regs / L2-hot); A in LDS bf16 with XOR-swizzle; T14 async stage;
// per-slice partial outputs merged downstream (no global atomics).

#define NEGV (-1000000000.0f)

typedef __attribute__((ext_vector_type(8))) short short8;
typedef __attribute__((ext_vector_type(4))) float f32x4;

__device__ inline ushort f2bf(float f) {
  union { float f; unsigned u; } a;
  a.f = f;
  unsigned u = a.u;
  return (ushort)((u + 0x7FFFu + ((u >> 16) & 1u)) >> 16);  // RNE
}

// ---------------- prep: pre-summed weight columns (8 blocks) ----------------
__global__ __launch_bounds__(256) void prep_kernel(const float* __restrict__ Wq_w,
                                                   const float* __restrict__ Wq_b,
                                                   const float* __restrict__ Wk_w,
                                                   const float* __restrict__ Wk_b,
                                                   float* __restrict__ sqw, float* __restrict__ sqb,
                                                   float* __restrict__ skw, float* __restrict__ skb) {
  int idx = blockIdx.x * 256 + threadIdx.x;  // 0..2047
  int i = idx >> 3, m = idx & 7;
  const float4* qw = reinterpret_cast<const float4*>(Wq_w + i * 512 + m * 64);
  const float4* kw = reinterpret_cast<const float4*>(Wk_w + i * 512 + m * 64);
  float aq = 0.f, ak = 0.f;
  #pragma unroll
  for (int c4 = 0; c4 < 8; ++c4) {
    float4 x = qw[c4];
    float4 y = kw[c4];
    aq += x.x + x.y + x.z + x.w;
    ak += y.x + y.y + y.z + y.w;
  }
  sqw[i * 8 + m] = aq;
  skw[i * 8 + m] = ak;
  if (idx < 8) {
    float bq = 0.f, bk = 0.f;
    for (int c = 0; c < 32; ++c) { bq += Wq_b[idx * 64 + c]; bk += Wk_b[idx * 64 + c]; }
    sqb[idx] = bq;
    skb[idx] = bk;
  }
}

// ---------------- Wv -> bf16 swizzled to wave-fragment order ----------------
// wvtf[((nt*8 + ks)*64 + lane)*8 + e] = bf16(Wv[(ks*32 + (lane>>4)*8 + e)*512 + nt*16 + (lane&15)])
__global__ __launch_bounds__(512) void wvt_kernel(const float* __restrict__ Wv,
                                                  ushort* __restrict__ wvtf) {
  int idx = blockIdx.x * 512 + threadIdx.x;  // 0..131071
  int e = idx & 7;
  int lane = (idx >> 3) & 63;
  int ks = (idx >> 9) & 7;
  int nt = idx >> 12;
  int r0 = lane & 15, kb = lane >> 4;
  int k = ks * 32 + kb * 8 + e;
  int ch = nt * 16 + r0;
  wvtf[idx] = f2bf(Wv[k * 512 + ch]);
}

// ---------------- qsum[b][h][t][s] = sum_c q_s ----------------
__global__ __launch_bounds__(256) void qsum_kernel(const float* __restrict__ q,
                                                   const float* __restrict__ sqw,
                                                   const float* __restrict__ sqb,
                                                   float* __restrict__ qsum) {
  int blk = blockIdx.x;  // b*32 + fo2
  int fo2 = blk & 31;
  int b = blk >> 5;
  __shared__ float lq[22][257];
  __shared__ float lw[2048];
  __shared__ float lb[8];
  int tid = threadIdx.x;
  const float* qb = q + (size_t)blk * (22 * 256);
  #pragma unroll
  for (int j = 0; j < 22; ++j) lq[j][tid] = qb[j * 256 + tid];
  for (int r = tid; r < 2048; r += 256) lw[r] = sqw[r];
  if (tid < 8) lb[tid] = sqb[tid];
  __syncthreads();
  if (tid < 176) {
    int j2 = tid >> 3, m = tid & 7;
    float acc = lb[m];
    for (int i = 0; i < 256; ++i) acc += lq[j2][i] * lw[i * 8 + m];
    int lf = (fo2 & 3) * 11264 + j2 * 512 + m * 64;
    int t = lf / 1408;
    int s = (lf % 1408) >> 6;
    int h = fo2 >> 2;
    qsum[(((size_t)b * 8 + h) * 32 + t) * 22 + s] = acc;
  }
}

// ---------------- ksumraw[b][h][f][j] = sum_d k_s ----------------
__global__ __launch_bounds__(256) void ksum_kernel(const float* __restrict__ k,
                                                   const float* __restrict__ skw,
                                                   const float* __restrict__ skb,
                                                   float* __restrict__ ksumraw) {
  int blk = blockIdx.x;  // b*16 + f2
  int f2 = blk & 15;
  int b = blk >> 4;
  __shared__ float lk[22][257];
  __shared__ float lw[2048];
  __shared__ float lb[8];
  int tid = threadIdx.x;
  const float* kb = k + (size_t)blk * (22 * 256);
  #pragma unroll
  for (int j = 0; j < 22; ++j) lk[j][tid] = kb[j * 256 + tid];
  for (int r = tid; r < 2048; r += 256) lw[r] = skw[r];
  if (tid < 8) lb[tid] = skb[tid];
  __syncthreads();
  if (tid < 176) {
    int j2 = tid >> 3, m = tid & 7;
    float acc = lb[m];
    for (int i = 0; i < 256; ++i) acc += lk[j2][i] * lw[i * 8 + m];
    int lf = (f2 & 1) * 11264 + j2 * 512 + m * 64;
    int floc = lf / 1408;
    int j = (lf % 1408) >> 6;
    int h = f2 >> 1;
    ksumraw[(((size_t)b * 8 + h) * 16 + floc) * 22 + j] = acc;
  }
}

// ---------------- ksum_s = conv_s over ksumraw ----------------
__global__ void convk_kernel(const float* __restrict__ ksumraw, const float* __restrict__ csw,
                             const float* __restrict__ csb, float* __restrict__ ksum_s) {
  size_t idx = (size_t)blockIdx.x * 256 + threadIdx.x;
  if (idx >= (size_t)256 * 8 * 32 * 22) return;
  int j = (int)(idx % 22);
  size_t r = idx / 22;
  int o = (int)(r % 32);
  size_t bh = r / 32;
  float acc = 32.0f * csb[o];
  #pragma unroll
  for (int f = 0; f < 16; ++f) acc += csw[o * 16 + f] * ksumraw[(bh * 16 + f) * 22 + j];
  ksum_s[idx] = acc;
}

// ---------------- vproj2: MFMA GEMM + scatter-reduce, sliced ----------------
#define STAGE_WRITE(rr, pa, pb)                                               \
  {                                                                           \
    int row_ = (rr) >> 5;                                                     \
    int gp_ = ((rr) & 31) ^ (row_ & 7);                                       \
    short8 u_;                                                                \
    u_[0] = (short)f2bf(pa.x); u_[1] = (short)f2bf(pa.y);                     \
    u_[2] = (short)f2bf(pa.z); u_[3] = (short)f2bf(pa.w);                     \
    u_[4] = (short)f2bf(pb.x); u_[5] = (short)f2bf(pb.y);                     \
    u_[6] = (short)f2bf(pb.z); u_[7] = (short)f2bf(pb.w);                     \
    *reinterpret_cast<short8*>(&lA[row_ * 256 + gp_ * 8]) = u_;               \
  }

__global__ __launch_bounds__(512, 4) void vproj2_kernel(const float* __restrict__ v,
                                                        const ushort* __restrict__ wvtf,
                                                        const float* __restrict__ Wv_b,
                                                        float* __restrict__ vs_part,
                                                        float* __restrict__ vt_part) {
  int bx = blockIdx.x;        // 512 blocks: ns = bx>>8 (n-slice), g = bx&255 (bh group)
  int ns = bx >> 8, g = bx & 255;
  int tid = threadIdx.x, lane = tid & 63, w = tid >> 6;
  int r0 = lane & 15, kb = lane >> 4;
  __shared__ ushort lA[48 * 256];   // [row][k] bf16, granule-swizzled: gp = gl ^ (row&7)
  __shared__ float vs_acc[512];
  __shared__ float vt_acc[704];

  int ntg0 = ns * 16 + w * 2;       // this wave's first global n-tile
  float bias0 = Wv_b[ntg0 * 16 + r0];
  float bias1 = Wv_b[(ntg0 + 1) * 16 + r0];
  const ushort* wb0 = wvtf + ((size_t)ntg0 * 8 * 64 + lane) * 8;
  const ushort* wb1 = wvtf + ((size_t)(ntg0 + 1) * 8 * 64 + lane) * 8;

  const float* vbase = v + (size_t)g * 8 * 11264;   // 8 bh * 44*256 floats

  // prologue: stage bh=0 (44 rows x 256 -> bf16, swizzled)
  {
    const float* vsrc = vbase;
    float4 p0a = *reinterpret_cast<const float4*>(vsrc + (size_t)tid * 8);
    float4 p0b = *reinterpret_cast<const float4*>(vsrc + (size_t)tid * 8 + 4);
    float4 p1a = *reinterpret_cast<const float4*>(vsrc + (size_t)(tid + 512) * 8);
    float4 p1b = *reinterpret_cast<const float4*>(vsrc + (size_t)(tid + 512) * 8 + 4);
    float4 p2a = {0, 0, 0, 0}, p2b = {0, 0, 0, 0};
    if (tid < 384) {
      p2a = *reinterpret_cast<const float4*>(vsrc + (size_t)(tid + 1024) * 8);
      p2b = *reinterpret_cast<const float4*>(vsrc + (size_t)(tid + 1024) * 8 + 4);
    }
    STAGE_WRITE(tid, p0a, p0b);
    STAGE_WRITE(tid + 512, p1a, p1b);
    if (tid < 384) STAGE_WRITE(tid + 1024, p2a, p2b);
  }
  vs_acc[tid] = 0.f;
  for (int rr = tid; rr < 704; rr += 512) vt_acc[rr] = 0.f;
  __syncthreads();

  for (int i = 0; i < 8; ++i) {
    f32x4 acc00 = {0,0,0,0}, acc01 = {0,0,0,0}, acc02 = {0,0,0,0};
    f32x4 acc10 = {0,0,0,0}, acc11 = {0,0,0,0}, acc12 = {0,0,0,0};
    #pragma unroll
    for (int ks = 0; ks < 8; ++ks) {
      int go = (((ks * 4 + kb) ^ (r0 & 7)) * 8);
      short8 b0 = *reinterpret_cast<const short8*>(wb0 + (size_t)ks * 512);
      short8 b1 = *reinterpret_cast<const short8*>(wb1 + (size_t)ks * 512);
      short8 a0 = *reinterpret_cast<const short8*>(&lA[r0 * 256 + go]);
      short8 a1 = *reinterpret_cast<const short8*>(&lA[(16 + r0) * 256 + go]);
      short8 a2 = *reinterpret_cast<const short8*>(&lA[(32 + r0) * 256 + go]);
      acc00 = __builtin_amdgcn_mfma_f32_16x16x32_bf16(a0, b0, acc00, 0, 0, 0);
      acc01 = __builtin_amdgcn_mfma_f32_16x16x32_bf16(a1, b0, acc01, 0, 0, 0);
      acc02 = __builtin_amdgcn_mfma_f32_16x16x32_bf16(a2, b0, acc02, 0, 0, 0);
      acc10 = __builtin_amdgcn_mfma_f32_16x16x32_bf16(a0, b1, acc10, 0, 0, 0);
      acc11 = __builtin_amdgcn_mfma_f32_16x16x32_bf16(a1, b1, acc11, 0, 0, 0);
      acc12 = __builtin_amdgcn_mfma_f32_16x16x32_bf16(a2, b1, acc12, 0, 0, 0);
    }
    __syncthreads();  // all waves done reading lA

    // T14: issue next bh's global loads now; write after scatter
    float4 p0a = {0,0,0,0}, p0b = {0,0,0,0}, p1a = {0,0,0,0}, p1b = {0,0,0,0};
    float4 p2a = {0,0,0,0}, p2b = {0,0,0,0};
    if (i < 7) {
      const float* vsrc = vbase + (size_t)(i + 1) * 11264;
      p0a = *reinterpret_cast<const float4*>(vsrc + (size_t)tid * 8);
      p0b = *reinterpret_cast<const float4*>(vsrc + (size_t)tid * 8 + 4);
      p1a = *reinterpret_cast<const float4*>(vsrc + (size_t)(tid + 512) * 8);
      p1b = *reinterpret_cast<const float4*>(vsrc + (size_t)(tid + 512) * 8 + 4);
      if (tid < 384) {
        p2a = *reinterpret_cast<const float4*>(vsrc + (size_t)(tid + 1024) * 8);
        p2b = *reinterpret_cast<const float4*>(vsrc + (size_t)(tid + 1024) * 8 + 4);
      }
    }

    // scatter-reduce into LDS accumulators
    #pragma unroll
    for (int n2 = 0; n2 < 2; ++n2) {
      int ch = (ntg0 + n2) * 16 + r0;
      int c6 = ch >> 6, d = ch & 63;
      float bias = n2 ? bias1 : bias0;
      #pragma unroll
      for (int m = 0; m < 3; ++m) {
        #pragma unroll
        for (int reg = 0; reg < 4; ++reg) {
          int gr = m * 16 + kb * 4 + reg;  // D row = (lane>>4)*4 + reg (m89-verified)
          if (gr >= 44) continue;
          int f2loc = (gr >= 22) ? 1 : 0;
          int j = gr - f2loc * 22;
          int fj = f2loc * 176 + j * 8 + c6;
          int f = fj / 22, jj = fj - f * 22;
          f32x4 a = (n2 == 0) ? ((m == 0) ? acc00 : (m == 1) ? acc01 : acc02)
                              : ((m == 0) ? acc10 : (m == 1) ? acc11 : acc12);
          float val = a[reg] + bias;
          if (d < 32)
            atomicAdd(&vs_acc[f * 32 + d], val);
          else
            atomicAdd(&vt_acc[jj * 32 + (d - 32)], val);
        }
      }
    }

    if (i < 7) {
      STAGE_WRITE(tid, p0a, p0b);
      STAGE_WRITE(tid + 512, p1a, p1b);
      if (tid < 384) STAGE_WRITE(tid + 1024, p2a, p2b);
    }
    __syncthreads();  // scatter done; lA(i+1) staged

    int bh = g * 8 + i;
    vs_part[((size_t)ns * 2048 + bh) * 512 + tid] = vs_acc[tid];
    vs_acc[tid] = 0.f;
    for (int rr = tid; rr < 704; rr += 512) {
      vt_part[((size_t)ns * 2048 + bh) * 704 + rr] = vt_acc[rr];
      vt_acc[rr] = 0.f;
    }
    __syncthreads();  // writeout+zero visible before next scatter
  }
}

// ---------------- vtmerge: vtsum = vt_part[0] + vt_part[1] ----------------
__global__ void vtmerge_kernel(const float* __restrict__ vt_part, float* __restrict__ vtsum) {
  size_t idx = (size_t)blockIdx.x * 256 + threadIdx.x;
  if (idx >= (size_t)1441792) return;
  vtsum[idx] = vt_part[idx] + vt_part[idx + 1441792];
}

// ---------------- vssum = conv_s over (vs_part0 + vs_part1) ----------------
__global__ void convv_kernel(const float* __restrict__ vs_part, const float* __restrict__ csw,
                             const float* __restrict__ csb, float* __restrict__ vssum) {
  size_t idx = (size_t)blockIdx.x * 256 + threadIdx.x;
  if (idx >= (size_t)256 * 8 * 32 * 32) return;
  int d = (int)(idx & 31);
  size_t r = idx >> 5;
  int t = (int)(r & 31);
  size_t bh = r >> 5;
  float acc = 22.0f * csb[t];
  #pragma unroll
  for (int f = 0; f < 16; ++f) {
    size_t off = (bh * 16 + f) * 32 + d;
    acc += csw[t * 16 + f] * (vs_part[off] + vs_part[off + 1048576]);
  }
  vssum[idx] = acc;
}

// ---------------- final: diag softmax + assemble output ----------------
__global__ __launch_bounds__(256) void final_kernel(const float* __restrict__ qsum,
                                                    const float* __restrict__ ksum_s,
                                                    const float* __restrict__ vssum,
                                                    const float* __restrict__ vtsum,
                                                    const int* __restrict__ mask_s,
                                                    float* __restrict__ out) {
  int blk = blockIdx.x;  // b*32 + t
  int t = blk & 31;
  int b = blk >> 5;
  __shared__ float ql[8][22], kl[8][22], vsl[8][32], dg[8][22];
  __shared__ float vtl[8][704];
  __shared__ int msk[484];
  int tid = threadIdx.x;
  size_t bbase = (size_t)b * 8;
  if (tid < 176) {
    int h = tid / 22, s = tid % 22;
    ql[h][s] = qsum[((bbase + h) * 32 + t) * 22 + s];
    kl[h][s] = ksum_s[((bbase + h) * 32 + t) * 22 + s];
  }
  {
    int h = tid >> 5, d = tid & 31;
    vsl[h][d] = vssum[((bbase + h) * 32 + t) * 32 + d];
  }
  for (int idx = tid; idx < 5632; idx += 256) {
    int h = idx / 704, r = idx % 704;
    vtl[h][r] = vtsum[(bbase + h) * 704 + r];
  }
  for (int idx = tid; idx < 484; idx += 256) msk[idx] = mask_s[idx];
  __syncthreads();
  if (tid < 176) {
    int h = tid / 22, s = tid % 22;
    float qv = ql[h][s];
    float mx = -3.0e38f;
    #pragma unroll
    for (int u = 0; u < 22; ++u) {
      float av = msk[s * 22 + u] ? qv * kl[h][u] : NEGV;
      mx = fmaxf(mx, av);
    }
    float den = 0.f;
    #pragma unroll
    for (int u = 0; u < 22; ++u) {
      float av = msk[s * 22 + u] ? qv * kl[h][u] : NEGV;
      den += expf(av - mx);
    }
    float as = msk[s * 22 + s] ? qv * kl[h][s] : NEGV;
    dg[h][s] = expf(as - mx) / den;
  }
  __syncthreads();
  float* ob = out + (size_t)blk * (22 * 512);
  for (int idx = tid; idx < 11264; idx += 256) {
    int s = idx >> 9;
    int ch = idx & 511;
    int h = ch >> 6;
    int d = ch & 63;
    float val = (d < 32) ? dg[h][s] * vsl[h][d] : vtl[h][s * 32 + (d & 31)];
    ob[idx] = val;
  }
}

extern "C" void kernel_launch(void* const* d_in, const int* in_sizes, int n_in,
                              void* d_out, int out_size, void* d_ws, size_t ws_size,
                              hipStream_t stream) {
  const float* q = (const float*)d_in[0];
  const float* k = (const float*)d_in[1];
  const float* v = (const float*)d_in[2];
  const int* mask_s = (const int*)d_in[3];
  const float* Wq_w = (const float*)d_in[5];
  const float* Wq_b = (const float*)d_in[6];
  const float* Wk_w = (const float*)d_in[7];
  const float* Wk_b = (const float*)d_in[8];
  const float* Wv_w = (const float*)d_in[9];
  const float* Wv_b = (const float*)d_in[10];
  const float* csw = (const float*)d_in[11];
  const float* csb = (const float*)d_in[12];
  float* out = (float*)d_out;

  float* ws = (float*)d_ws;
  float* sqw = ws;                          // 2048
  float* sqb = sqw + 2048;                  // 8
  float* skw = sqb + 8;                     // 2048
  float* skb = skw + 2048;                  // 8  -> 4112
  ushort* wvtf = (ushort*)(skb + 8);        // 131072 ushorts = 65536 floats
  float* qsum = (float*)(wvtf + 131072);    // 1441792
  float* ksumraw = qsum + 1441792;          // 720896
  float* ksum_s = ksumraw + 720896;         // 1441792
  float* vs_part = ksum_s + 1441792;        // 2*2048*512 = 2097152
  float* vt_part = vs_part + 2097152;       // 2*2048*704 = 2883584
  float* vtsum = vt_part + 2883584;         // 1441792
  float* vssum = vtsum + 1441792;           // 2097152

  hipLaunchKernelGGL(prep_kernel, dim3(8), dim3(256), 0, stream,
                     Wq_w, Wq_b, Wk_w, Wk_b, sqw, sqb, skw, skb);
  hipLaunchKernelGGL(wvt_kernel, dim3(256), dim3(512), 0, stream, Wv_w, wvtf);
  hipLaunchKernelGGL(qsum_kernel, dim3(256 * 32), dim3(256), 0, stream, q, sqw, sqb, qsum);
  hipLaunchKernelGGL(ksum_kernel, dim3(256 * 16), dim3(256), 0, stream, k, skw, skb, ksumraw);
  hipLaunchKernelGGL(convk_kernel, dim3(5632), dim3(256), 0, stream, ksumraw, csw, csb, ksum_s);
  hipLaunchKernelGGL(vproj2_kernel, dim3(512), dim3(512), 0, stream,
                     v, wvtf, Wv_b, vs_part, vt_part);
  hipLaunchKernelGGL(vtmerge_kernel, dim3(5632), dim3(256), 0, stream, vt_part, vtsum);
  hipLaunchKernelGGL(convv_kernel, dim3(8192), dim3(256), 0, stream, vs_part, csw, csb, vssum);
  hipLaunchKernelGGL(final_kernel, dim3(8192), dim3(256), 0, stream,
                     qsum, ksum_s, vssum, vtsum, mask_s, out);
}